// Round 7
// baseline (240.833 us; speedup 1.0000x reference)
//
#include <hip/hip_runtime.h>
#include <hip/hip_bf16.h>

#define D_DIM 1024
#define F_DIM 1024
#define NTOK  4096
#define NEXP  8
#define CAP   4096

typedef __attribute__((ext_vector_type(8))) short bf16x8;
typedef __attribute__((ext_vector_type(4))) float f32x4;
typedef __attribute__((ext_vector_type(8))) unsigned short u16x8;

__device__ __forceinline__ unsigned short f2bf(float f) {
    unsigned int u = __float_as_uint(f);
    u = u + 0x7fffu + ((u >> 16) & 1u);
    return (unsigned short)(u >> 16);
}

__device__ __forceinline__ void async_copy16(void* lds, const void* gsrc) {
    __builtin_amdgcn_global_load_lds(
        (const __attribute__((address_space(1))) unsigned int*)gsrc,
        (__attribute__((address_space(3))) unsigned int*)lds, 16, 0, 0);
}

// ---------------- f32 -> bf16 conversion (8 elems/thread) ----------------
__global__ __launch_bounds__(256) void cvt_kernel(const float* __restrict__ in,
                                                  unsigned short* __restrict__ out, int n) {
    int i = (blockIdx.x * 256 + threadIdx.x) * 8;
    if (i >= n) return;
    const float4* p = (const float4*)(in + i);
    float4 a = p[0], b = p[1];
    u16x8 r;
    r[0] = f2bf(a.x); r[1] = f2bf(a.y); r[2] = f2bf(a.z); r[3] = f2bf(a.w);
    r[4] = f2bf(b.x); r[5] = f2bf(b.y); r[6] = f2bf(b.z); r[7] = f2bf(b.w);
    *(u16x8*)(out + i) = r;
}

// ---------------- router logits: one wave per token, f64 accumulation ----------------
__global__ __launch_bounds__(256) void logits_kernel(
    const float* __restrict__ x, const float* __restrict__ rw,
    float* __restrict__ logits)
{
    const int wave = threadIdx.x >> 6, lane = threadIdx.x & 63;
    const int t = blockIdx.x * 4 + wave;
    double s[NEXP];
    #pragma unroll
    for (int e = 0; e < NEXP; ++e) s[e] = 0.0;
    const float* xp = x + (size_t)t * D_DIM;
    for (int kk = 0; kk < D_DIM; kk += 64) {
        float xv = xp[kk + lane];
        #pragma unroll
        for (int e = 0; e < NEXP; ++e)
            s[e] += (double)xv * (double)rw[e * D_DIM + kk + lane];
    }
    #pragma unroll
    for (int e = 0; e < NEXP; ++e) {
        double v = s[e];
        for (int off = 32; off; off >>= 1) v += __shfl_xor(v, off, 64);
        s[e] = v;
    }
    if (lane == 0) {
        #pragma unroll
        for (int e = 0; e < NEXP; ++e) logits[(size_t)t * NEXP + e] = (float)s[e];
    }
}

// ---------------- assign: top-2 + softmax + LDS-aggregated expert lists ----------------
__global__ __launch_bounds__(256) void assign_kernel(
    const float* __restrict__ logits, const float* __restrict__ bias,
    int* counts, int* list, float* wlist)
{
    __shared__ int lcnt[NEXP];
    __shared__ int lbase[NEXP];
    const int tid = threadIdx.x;
    const int t = blockIdx.x * 256 + tid;
    if (tid < NEXP) lcnt[tid] = 0;
    __syncthreads();

    float lg[NEXP], b2[NEXP];
    #pragma unroll
    for (int e = 0; e < NEXP; ++e) {
        lg[e] = logits[(size_t)t * NEXP + e];
        b2[e] = lg[e] + bias[e];
    }
    int i0 = 0; float b0v = b2[0], l0v = lg[0];
    #pragma unroll
    for (int e = 1; e < NEXP; ++e)
        if (b2[e] > b0v) { b0v = b2[e]; l0v = lg[e]; i0 = e; }
    int i1 = -1; float b1v = 0.f, l1v = 0.f;
    #pragma unroll
    for (int e = 0; e < NEXP; ++e) {
        if (e == i0) continue;
        bool take = (i1 < 0) || (b2[e] > b1v);
        if (take) { i1 = e; b1v = b2[e]; l1v = lg[e]; }
    }
    float m = fmaxf(l0v, l1v);
    float e0 = expf(l0v - m), e1 = expf(l1v - m);
    float inv = 1.0f / (e0 + e1);

    int lp0 = atomicAdd(&lcnt[i0], 1);
    int lp1 = atomicAdd(&lcnt[i1], 1);
    __syncthreads();
    if (tid < NEXP) lbase[tid] = atomicAdd(&counts[tid], lcnt[tid]);
    __syncthreads();

    int p0 = lbase[i0] + lp0;
    list[i0 * CAP + p0] = t; wlist[i0 * CAP + p0] = e0 * inv;
    int p1 = lbase[i1] + lp1;
    list[i1 * CAP + p1] = t; wlist[i1 * CAP + p1] = e1 * inv;
}

// ======== GEMM machinery: BM=128, BN=128, BK=64, DOUBLE-buffer with ========
// ======== counted-vmcnt pipeline (T4): never drain to 0 mid-loop.   ========
// ======== XOR slot swizzle phys = slot ^ (row&7) (verified 0-conflict) ========
//
// A and B each: 16 chunks of 8 rows x 128B; wave w stages chunks w*4+i.
// lane l -> row-in-chunk l>>3, phys 16B-slot l&7 (linear LDS dest);
// global source slot pre-swizzled: g = (l&7)^(l>>3). 8 loads/lane/tile.
#define STAGE(AB, BB, k0)                                                   \
    do {                                                                    \
        _Pragma("unroll")                                                   \
        for (int i = 0; i < 4; ++i) {                                       \
            async_copy16(&AB[(wave * 4 + i) * 512], ap[i] + (k0));          \
            async_copy16(&BB[(wave * 4 + i) * 512], bp_[i] + (k0));         \
        }                                                                   \
    } while (0)

// per kk-slice: frag row = base + (lane&15); logical slot s = kk*4+(lane>>4),
// phys = s ^ (row&7) = s ^ (lane&7).  (verified PASS + 0 conflicts, r4/r6)
#define COMPUTE(AB, BB)                                                     \
    do {                                                                    \
        _Pragma("unroll")                                                   \
        for (int kk = 0; kk < 2; ++kk) {                                    \
            bf16x8 af[4], bfv[4];                                           \
            const int phys = (((kk * 4) + (lane >> 4)) ^ (lane & 7)) * 8;   \
            _Pragma("unroll")                                               \
            for (int m = 0; m < 4; ++m)                                     \
                af[m] = *(const bf16x8*)&AB[(wr * 64 + m * 16 + (lane & 15)) * 64 + phys]; \
            _Pragma("unroll")                                               \
            for (int n = 0; n < 4; ++n)                                     \
                bfv[n] = *(const bf16x8*)&BB[(wc * 64 + n * 16 + (lane & 15)) * 64 + phys]; \
            _Pragma("unroll")                                               \
            for (int m = 0; m < 4; ++m)                                     \
                _Pragma("unroll")                                           \
                for (int n = 0; n < 4; ++n)                                 \
                    acc[m][n] = __builtin_amdgcn_mfma_f32_16x16x32_bf16(af[m], bfv[n], acc[m][n], 0, 0, 0); \
        }                                                                   \
    } while (0)

// Pipelined K-loop: tile t's 8 loads are waited with vmcnt(8) (leaving tile
// t+1's 8 in flight) ~2 phases after issue. Raw s_barrier (no implicit drain).
#define KLOOP()                                                             \
    do {                                                                    \
        STAGE(As0, Bs0, 0);                                                 \
        STAGE(As1, Bs1, 64);                                                \
        _Pragma("unroll")                                                   \
        for (int t = 0; t < 16; ++t) {                                      \
            if (t < 15) asm volatile("s_waitcnt vmcnt(8)" ::: "memory");    \
            else        asm volatile("s_waitcnt vmcnt(0)" ::: "memory");    \
            __builtin_amdgcn_s_barrier();                                   \
            if ((t & 1) == 0) COMPUTE(As0, Bs0);                            \
            else              COMPUTE(As1, Bs1);                            \
            __builtin_amdgcn_s_barrier();                                   \
            if (t + 2 < 16) {                                               \
                if ((t & 1) == 0) STAGE(As0, Bs0, (t + 2) * 64);            \
                else              STAGE(As1, Bs1, (t + 2) * 64);            \
            }                                                               \
        }                                                                   \
    } while (0)

// ---------------- grouped GEMM1: H = gelu(Xg @ W1_e^T), bf16 out ----------------
__global__ __launch_bounds__(256) void gemm1_kernel(
    const unsigned short* __restrict__ xb,
    const unsigned short* __restrict__ w1b,
    const int* __restrict__ counts,
    const int* __restrict__ list,
    unsigned short* __restrict__ H)
{
    const int e  = blockIdx.y >> 5;
    const int rb = blockIdx.y & 31;
    const int ne = counts[e];
    if (rb * 128 >= ne) return;
    const int row0 = rb * 128;
    const int n0 = blockIdx.x * 128;
    int hbase = 0;
    #pragma unroll
    for (int ee = 0; ee < NEXP; ++ee) if (ee < e) hbase += counts[ee];

    __shared__ __align__(16) unsigned short As0[128 * 64], As1[128 * 64];
    __shared__ __align__(16) unsigned short Bs0[128 * 64], Bs1[128 * 64];
    __shared__ int toks[128];

    const int tid = threadIdx.x;
    if (tid < 128) {
        int i = row0 + tid;
        if (i >= ne) i = ne - 1;
        toks[tid] = list[e * CAP + i];
    }
    __syncthreads();   // also drains vmcnt to 0 before the pipelined loop

    const int wave = tid >> 6, lane = tid & 63;
    const int wr = wave >> 1, wc = wave & 1;

    const int lr  = lane >> 3;
    const int swz = ((lane & 7) ^ lr) * 8;
    const unsigned short* ap[4];
    const unsigned short* bp_[4];
    const unsigned short* wbase = w1b + (size_t)e * F_DIM * D_DIM;
    #pragma unroll
    for (int i = 0; i < 4; ++i) {
        int r = wave * 32 + i * 8 + lr;
        ap[i]  = xb + (size_t)toks[r] * D_DIM + swz;
        bp_[i] = wbase + (size_t)(n0 + r) * D_DIM + swz;
    }

    f32x4 acc[4][4];
    #pragma unroll
    for (int m = 0; m < 4; ++m)
        #pragma unroll
        for (int n = 0; n < 4; ++n) acc[m][n] = (f32x4){0.f, 0.f, 0.f, 0.f};

    KLOOP();

    #pragma unroll
    for (int m = 0; m < 4; ++m) {
        #pragma unroll
        for (int j = 0; j < 4; ++j) {
            int ri = wr * 64 + m * 16 + (lane >> 4) * 4 + j;
            int i = row0 + ri;
            if (i < ne) {
                unsigned short* hp = H + (size_t)(hbase + i) * F_DIM + n0 + wc * 64;
                #pragma unroll
                for (int n = 0; n < 4; ++n) {
                    float v = acc[m][n][j];
                    float g = 0.5f * v * (1.0f + erff(v * 0.70710678118654752f));
                    hp[n * 16 + (lane & 15)] = f2bf(g);
                }
            }
        }
    }
}

// ---------------- grouped GEMM2: out += w * (H @ W2_e^T), atomic f32 ----------------
__global__ __launch_bounds__(256) void gemm2_kernel(
    const unsigned short* __restrict__ H,
    const unsigned short* __restrict__ w2b,
    const int* __restrict__ counts,
    const int* __restrict__ list, const float* __restrict__ wlist,
    float* __restrict__ out)
{
    const int e  = blockIdx.y >> 5;
    const int rb = blockIdx.y & 31;
    const int ne = counts[e];
    if (rb * 128 >= ne) return;
    const int row0 = rb * 128;
    const int n0 = blockIdx.x * 128;
    int hbase = 0;
    #pragma unroll
    for (int ee = 0; ee < NEXP; ++ee) if (ee < e) hbase += counts[ee];

    __shared__ __align__(16) unsigned short As0[128 * 64], As1[128 * 64];
    __shared__ __align__(16) unsigned short Bs0[128 * 64], Bs1[128 * 64];
    __shared__ int toks[128];
    __shared__ float wts[128];

    const int tid = threadIdx.x;
    if (tid < 128) {
        int i = row0 + tid;
        if (i >= ne) i = ne - 1;
        toks[tid] = list[e * CAP + i];
        wts[tid]  = wlist[e * CAP + i];
    }
    __syncthreads();   // also drains vmcnt to 0 before the pipelined loop

    const int wave = tid >> 6, lane = tid & 63;
    const int wr = wave >> 1, wc = wave & 1;

    const int lr  = lane >> 3;
    const int swz = ((lane & 7) ^ lr) * 8;
    const unsigned short* ap[4];
    const unsigned short* bp_[4];
    const unsigned short* wbase = w2b + (size_t)e * D_DIM * F_DIM;
    #pragma unroll
    for (int i = 0; i < 4; ++i) {
        int r = wave * 32 + i * 8 + lr;
        ap[i]  = H + (size_t)(hbase + row0 + r) * F_DIM + swz;
        bp_[i] = wbase + (size_t)(n0 + r) * F_DIM + swz;
    }

    f32x4 acc[4][4];
    #pragma unroll
    for (int m = 0; m < 4; ++m)
        #pragma unroll
        for (int n = 0; n < 4; ++n) acc[m][n] = (f32x4){0.f, 0.f, 0.f, 0.f};

    KLOOP();

    #pragma unroll
    for (int m = 0; m < 4; ++m) {
        #pragma unroll
        for (int j = 0; j < 4; ++j) {
            int ri = wr * 64 + m * 16 + (lane >> 4) * 4 + j;
            int i = row0 + ri;
            if (i < ne) {
                int t = toks[ri];
                float wt = wts[ri];
                float* op = out + (size_t)t * D_DIM + n0 + wc * 64;
                #pragma unroll
                for (int n = 0; n < 4; ++n)
                    atomicAdd(&op[n * 16 + (lane & 15)], wt * acc[m][n][j]);
            }
        }
    }
}

extern "C" void kernel_launch(void* const* d_in, const int* in_sizes, int n_in,
                              void* d_out, int out_size, void* d_ws, size_t ws_size,
                              hipStream_t stream)
{
    const float* x    = (const float*)d_in[0];
    const float* bias = (const float*)d_in[1];
    const float* rw   = (const float*)d_in[2];
    const float* w1   = (const float*)d_in[3];
    const float* w2   = (const float*)d_in[4];
    float* out = (float*)d_out;

    char* ws = (char*)d_ws;
    size_t cur = 0;
    auto alloc = [&](size_t bytes) -> void* {
        void* p = (void*)(ws + cur);
        cur += (bytes + 255) & ~(size_t)255;
        return p;
    };
    unsigned short* xb   = (unsigned short*)alloc((size_t)NTOK * D_DIM * 2);
    unsigned short* w1b  = (unsigned short*)alloc((size_t)NEXP * F_DIM * D_DIM * 2);
    unsigned short* w2b  = (unsigned short*)alloc((size_t)NEXP * F_DIM * D_DIM * 2);
    unsigned short* Hb   = (unsigned short*)alloc((size_t)(NTOK * 2 + 128) * F_DIM * 2);
    float* logits = (float*)alloc((size_t)NTOK * NEXP * 4);
    int*   list   = (int*)alloc(NEXP * CAP * 4);
    float* wlist  = (float*)alloc(NEXP * CAP * 4);
    int*   counts = (int*)alloc(64);

    hipMemsetAsync(counts, 0, 64, stream);
    hipMemsetAsync(out, 0, (size_t)out_size * 4, stream);

    cvt_kernel<<<NTOK * D_DIM / 2048, 256, 0, stream>>>(x, xb, NTOK * D_DIM);
    cvt_kernel<<<NEXP * F_DIM * D_DIM / 2048, 256, 0, stream>>>(w1, w1b, NEXP * F_DIM * D_DIM);
    cvt_kernel<<<NEXP * F_DIM * D_DIM / 2048, 256, 0, stream>>>(w2, w2b, NEXP * F_DIM * D_DIM);
    logits_kernel<<<NTOK / 4, 256, 0, stream>>>(x, rw, logits);
    assign_kernel<<<NTOK / 256, 256, 0, stream>>>(logits, bias, counts, list, wlist);
    gemm1_kernel<<<dim3(8, 256), 256, 0, stream>>>(xb, w1b, counts, list, Hb);
    gemm2_kernel<<<dim3(8, 256), 256, 0, stream>>>(Hb, w2b, counts, list, wlist, out);
}

// Round 8
// 218.889 us; speedup vs baseline: 1.1003x; 1.1003x over previous
//
#include <hip/hip_runtime.h>
#include <hip/hip_bf16.h>

#define D_DIM 1024
#define F_DIM 1024
#define NTOK  4096
#define NEXP  8
#define CAP   4096
#define NGRP_X (NTOK * D_DIM / 8)
#define NGRP_W (NEXP * F_DIM * D_DIM / 8)

typedef __attribute__((ext_vector_type(8))) short bf16x8;
typedef __attribute__((ext_vector_type(4))) float f32x4;
typedef __attribute__((ext_vector_type(8))) unsigned short u16x8;

__device__ __forceinline__ unsigned short f2bf(float f) {
    unsigned int u = __float_as_uint(f);
    u = u + 0x7fffu + ((u >> 16) & 1u);
    return (unsigned short)(u >> 16);
}

__device__ __forceinline__ void async_copy16(void* lds, const void* gsrc) {
    __builtin_amdgcn_global_load_lds(
        (const __attribute__((address_space(1))) unsigned int*)gsrc,
        (__attribute__((address_space(3))) unsigned int*)lds, 16, 0, 0);
}

// ---------------- fused f32 -> bf16 conversion for x, w1, w2 (1 launch) ----------------
__global__ __launch_bounds__(256) void cvt3_kernel(
    const float* __restrict__ x, const float* __restrict__ w1, const float* __restrict__ w2,
    unsigned short* __restrict__ xb, unsigned short* __restrict__ w1b,
    unsigned short* __restrict__ w2b)
{
    long g = (long)blockIdx.x * 256 + threadIdx.x;   // 8-elem group id
    const float* src; unsigned short* dst; long o;
    if (g < NGRP_X)            { src = x;  dst = xb;  o = g; }
    else if (g < NGRP_X + NGRP_W) { src = w1; dst = w1b; o = g - NGRP_X; }
    else                       { src = w2; dst = w2b; o = g - NGRP_X - NGRP_W; }
    size_t i = (size_t)o * 8;
    const float4* p = (const float4*)(src + i);
    float4 a = p[0], b = p[1];
    u16x8 r;
    r[0] = f2bf(a.x); r[1] = f2bf(a.y); r[2] = f2bf(a.z); r[3] = f2bf(a.w);
    r[4] = f2bf(b.x); r[5] = f2bf(b.y); r[6] = f2bf(b.z); r[7] = f2bf(b.w);
    *(u16x8*)(dst + i) = r;
}

// ---------------- router logits: one wave per token, f64 accumulation ----------------
__global__ __launch_bounds__(256) void logits_kernel(
    const float* __restrict__ x, const float* __restrict__ rw,
    float* __restrict__ logits)
{
    const int wave = threadIdx.x >> 6, lane = threadIdx.x & 63;
    const int t = blockIdx.x * 4 + wave;
    double s[NEXP];
    #pragma unroll
    for (int e = 0; e < NEXP; ++e) s[e] = 0.0;
    const float* xp = x + (size_t)t * D_DIM;
    for (int kk = 0; kk < D_DIM; kk += 64) {
        float xv = xp[kk + lane];
        #pragma unroll
        for (int e = 0; e < NEXP; ++e)
            s[e] += (double)xv * (double)rw[e * D_DIM + kk + lane];
    }
    #pragma unroll
    for (int e = 0; e < NEXP; ++e) {
        double v = s[e];
        for (int off = 32; off; off >>= 1) v += __shfl_xor(v, off, 64);
        s[e] = v;
    }
    if (lane == 0) {
        #pragma unroll
        for (int e = 0; e < NEXP; ++e) logits[(size_t)t * NEXP + e] = (float)s[e];
    }
}

// ---------------- assign: top-2 + softmax + expert lists + per-token pair table ----------------
__global__ __launch_bounds__(256) void assign_kernel(
    const float* __restrict__ logits, const float* __restrict__ bias,
    int* counts, int* list, int* pairEP, float* pairW)
{
    __shared__ int lcnt[NEXP];
    __shared__ int lbase[NEXP];
    const int tid = threadIdx.x;
    const int t = blockIdx.x * 256 + tid;
    if (tid < NEXP) lcnt[tid] = 0;
    __syncthreads();

    float lg[NEXP], b2[NEXP];
    #pragma unroll
    for (int e = 0; e < NEXP; ++e) {
        lg[e] = logits[(size_t)t * NEXP + e];
        b2[e] = lg[e] + bias[e];
    }
    int i0 = 0; float b0v = b2[0], l0v = lg[0];
    #pragma unroll
    for (int e = 1; e < NEXP; ++e)
        if (b2[e] > b0v) { b0v = b2[e]; l0v = lg[e]; i0 = e; }
    int i1 = -1; float b1v = 0.f, l1v = 0.f;
    #pragma unroll
    for (int e = 0; e < NEXP; ++e) {
        if (e == i0) continue;
        bool take = (i1 < 0) || (b2[e] > b1v);
        if (take) { i1 = e; b1v = b2[e]; l1v = lg[e]; }
    }
    float m = fmaxf(l0v, l1v);
    float e0 = expf(l0v - m), e1 = expf(l1v - m);
    float inv = 1.0f / (e0 + e1);

    int lp0 = atomicAdd(&lcnt[i0], 1);
    int lp1 = atomicAdd(&lcnt[i1], 1);
    __syncthreads();
    if (tid < NEXP) lbase[tid] = atomicAdd(&counts[tid], lcnt[tid]);
    __syncthreads();

    int p0 = lbase[i0] + lp0;
    int p1 = lbase[i1] + lp1;
    list[i0 * CAP + p0] = t;
    list[i1 * CAP + p1] = t;
    pairEP[2 * t]     = (p0 << 3) | i0;   // position-in-expert + expert id
    pairEP[2 * t + 1] = (p1 << 3) | i1;
    pairW[2 * t]      = e0 * inv;
    pairW[2 * t + 1]  = e1 * inv;
}

// ======== GEMM machinery (EXACT r6 structure, proven 0-conflict): ========
// ======== BM=128, BN=64, BK=64, single-buffer, stage->sync->compute->sync, ========
// ======== XOR slot swizzle phys = slot ^ (row&7) ========
#define STAGE(AB, BB, k0)                                                   \
    do {                                                                    \
        _Pragma("unroll")                                                   \
        for (int i = 0; i < 4; ++i)                                         \
            async_copy16(&AB[(wave * 4 + i) * 512], ap[i] + (k0));          \
        _Pragma("unroll")                                                   \
        for (int i = 0; i < 2; ++i)                                         \
            async_copy16(&BB[(wave * 2 + i) * 512], bp_[i] + (k0));         \
    } while (0)

#define COMPUTE(AB, BB)                                                     \
    do {                                                                    \
        _Pragma("unroll")                                                   \
        for (int kk = 0; kk < 2; ++kk) {                                    \
            bf16x8 af[4], bfv[2];                                           \
            const int phys = (((kk * 4) + (lane >> 4)) ^ (lane & 7)) * 8;   \
            _Pragma("unroll")                                               \
            for (int m = 0; m < 4; ++m)                                     \
                af[m] = *(const bf16x8*)&AB[(wr * 64 + m * 16 + (lane & 15)) * 64 + phys]; \
            _Pragma("unroll")                                               \
            for (int n = 0; n < 2; ++n)                                     \
                bfv[n] = *(const bf16x8*)&BB[(wc * 32 + n * 16 + (lane & 15)) * 64 + phys]; \
            _Pragma("unroll")                                               \
            for (int m = 0; m < 4; ++m)                                     \
                _Pragma("unroll")                                           \
                for (int n = 0; n < 2; ++n)                                 \
                    acc[m][n] = __builtin_amdgcn_mfma_f32_16x16x32_bf16(af[m], bfv[n], acc[m][n], 0, 0, 0); \
        }                                                                   \
    } while (0)

// ---------------- grouped GEMM1: H = gelu(Xg @ W1_e^T), bf16 out ----------------
__global__ __launch_bounds__(256) void gemm1_kernel(
    const unsigned short* __restrict__ xb,
    const unsigned short* __restrict__ w1b,
    const int* __restrict__ counts,
    const int* __restrict__ list,
    unsigned short* __restrict__ H)
{
    const int e  = blockIdx.y >> 5;
    const int rb = blockIdx.y & 31;
    const int ne = counts[e];
    if (rb * 128 >= ne) return;
    const int row0 = rb * 128;
    const int n0 = blockIdx.x * 64;
    int hbase = 0;
    #pragma unroll
    for (int ee = 0; ee < NEXP; ++ee) if (ee < e) hbase += counts[ee];

    __shared__ __align__(16) unsigned short As[128 * 64];
    __shared__ __align__(16) unsigned short Bs[64 * 64];
    __shared__ int toks[128];

    const int tid = threadIdx.x;
    if (tid < 128) {
        int i = row0 + tid;
        if (i >= ne) i = ne - 1;
        toks[tid] = list[e * CAP + i];
    }
    __syncthreads();

    const int wave = tid >> 6, lane = tid & 63;
    const int wr = wave >> 1, wc = wave & 1;

    const int lr  = lane >> 3;
    const int swz = ((lane & 7) ^ lr) * 8;
    const unsigned short* ap[4];
    const unsigned short* bp_[2];
    const unsigned short* wbase = w1b + (size_t)e * F_DIM * D_DIM;
    #pragma unroll
    for (int i = 0; i < 4; ++i)
        ap[i] = xb + (size_t)toks[wave * 32 + i * 8 + lr] * D_DIM + swz;
    #pragma unroll
    for (int i = 0; i < 2; ++i)
        bp_[i] = wbase + (size_t)(n0 + wave * 16 + i * 8 + lr) * D_DIM + swz;

    f32x4 acc[4][2];
    #pragma unroll
    for (int m = 0; m < 4; ++m)
        #pragma unroll
        for (int n = 0; n < 2; ++n) acc[m][n] = (f32x4){0.f, 0.f, 0.f, 0.f};

    for (int k0 = 0; k0 < D_DIM; k0 += 64) {
        STAGE(As, Bs, k0);
        __syncthreads();
        COMPUTE(As, Bs);
        __syncthreads();
    }

    #pragma unroll
    for (int m = 0; m < 4; ++m) {
        #pragma unroll
        for (int j = 0; j < 4; ++j) {
            int ri = wr * 64 + m * 16 + (lane >> 4) * 4 + j;
            int i = row0 + ri;
            if (i < ne) {
                unsigned short* hp = H + (size_t)(hbase + i) * F_DIM + n0 + wc * 32;
                #pragma unroll
                for (int n = 0; n < 2; ++n) {
                    float v = acc[m][n][j];
                    float g = 0.5f * v * (1.0f + erff(v * 0.70710678118654752f));
                    hp[n * 16 + (lane & 15)] = f2bf(g);
                }
            }
        }
    }
}

// ---------------- grouped GEMM2: O2 = H @ W2_e^T (plain f32 stores, NO atomics) ----------------
__global__ __launch_bounds__(256) void gemm2_kernel(
    const unsigned short* __restrict__ H,
    const unsigned short* __restrict__ w2b,
    const int* __restrict__ counts,
    float* __restrict__ O2)
{
    const int e  = blockIdx.y >> 5;
    const int rb = blockIdx.y & 31;
    const int ne = counts[e];
    if (rb * 128 >= ne) return;
    const int row0 = rb * 128;
    const int n0 = blockIdx.x * 64;
    int hbase = 0;
    #pragma unroll
    for (int ee = 0; ee < NEXP; ++ee) if (ee < e) hbase += counts[ee];

    __shared__ __align__(16) unsigned short As[128 * 64];
    __shared__ __align__(16) unsigned short Bs[64 * 64];

    const int tid = threadIdx.x;
    const int wave = tid >> 6, lane = tid & 63;
    const int wr = wave >> 1, wc = wave & 1;

    const int lr  = lane >> 3;
    const int swz = ((lane & 7) ^ lr) * 8;
    const unsigned short* ap[4];
    const unsigned short* bp_[2];
    const unsigned short* wbase = w2b + (size_t)e * D_DIM * F_DIM;
    #pragma unroll
    for (int i = 0; i < 4; ++i)
        ap[i] = H + (size_t)(hbase + row0 + wave * 32 + i * 8 + lr) * F_DIM + swz;
    #pragma unroll
    for (int i = 0; i < 2; ++i)
        bp_[i] = wbase + (size_t)(n0 + wave * 16 + i * 8 + lr) * F_DIM + swz;

    f32x4 acc[4][2];
    #pragma unroll
    for (int m = 0; m < 4; ++m)
        #pragma unroll
        for (int n = 0; n < 2; ++n) acc[m][n] = (f32x4){0.f, 0.f, 0.f, 0.f};

    for (int k0 = 0; k0 < F_DIM; k0 += 64) {
        STAGE(As, Bs, k0);
        __syncthreads();
        COMPUTE(As, Bs);
        __syncthreads();
    }

    #pragma unroll
    for (int m = 0; m < 4; ++m) {
        #pragma unroll
        for (int j = 0; j < 4; ++j) {
            int ri = wr * 64 + m * 16 + (lane >> 4) * 4 + j;
            int i = row0 + ri;
            if (i < ne) {
                float* op = O2 + (size_t)(hbase + i) * D_DIM + n0 + wc * 32;
                #pragma unroll
                for (int n = 0; n < 2; ++n)
                    op[n * 16 + (lane & 15)] = acc[m][n][j];
            }
        }
    }
}

// ---------------- combine: out[t] = w0*O2[row0] + w1*O2[row1] ----------------
__global__ __launch_bounds__(256) void combine_kernel(
    const float* __restrict__ O2, const int* __restrict__ counts,
    const int* __restrict__ pairEP, const float* __restrict__ pairW,
    float* __restrict__ out)
{
    const int t = blockIdx.x;
    const int tid = threadIdx.x;
    int offs[NEXP];
    int a = 0;
    #pragma unroll
    for (int e = 0; e < NEXP; ++e) { offs[e] = a; a += counts[e]; }
    int ep0 = pairEP[2 * t], ep1 = pairEP[2 * t + 1];
    float w0 = pairW[2 * t], w1 = pairW[2 * t + 1];
    // static-index the offs lookup (rule #20: avoid runtime-indexed arrays)
    int e0 = ep0 & 7, e1 = ep1 & 7, o0 = 0, o1 = 0;
    #pragma unroll
    for (int e = 0; e < NEXP; ++e) {
        if (e == e0) o0 = offs[e];
        if (e == e1) o1 = offs[e];
    }
    size_t r0 = (size_t)(o0 + (ep0 >> 3)) * D_DIM;
    size_t r1 = (size_t)(o1 + (ep1 >> 3)) * D_DIM;
    float4 va = *(const float4*)(O2 + r0 + tid * 4);
    float4 vb = *(const float4*)(O2 + r1 + tid * 4);
    float4 r;
    r.x = w0 * va.x + w1 * vb.x;
    r.y = w0 * va.y + w1 * vb.y;
    r.z = w0 * va.z + w1 * vb.z;
    r.w = w0 * va.w + w1 * vb.w;
    *(float4*)(out + (size_t)t * D_DIM + tid * 4) = r;
}

extern "C" void kernel_launch(void* const* d_in, const int* in_sizes, int n_in,
                              void* d_out, int out_size, void* d_ws, size_t ws_size,
                              hipStream_t stream)
{
    const float* x    = (const float*)d_in[0];
    const float* bias = (const float*)d_in[1];
    const float* rw   = (const float*)d_in[2];
    const float* w1   = (const float*)d_in[3];
    const float* w2   = (const float*)d_in[4];
    float* out = (float*)d_out;

    char* ws = (char*)d_ws;
    // Layout (bytes, 256-aligned). O2 aliases xb+w1b (dead once gemm2 runs):
    //   [0,16M)      w2b
    //   [16M,33.3M)  Hb   (8320 rows x 1024 bf16)
    //   [33.3M,67.4M) O2  (8320 rows x 1024 f32); xb at O2+0 (8MB), w1b at O2+8MB (16MB)
    //   tail: logits, list, pairEP, pairW, counts
    unsigned short* w2b = (unsigned short*)(ws);
    unsigned short* Hb  = (unsigned short*)(ws + 16777216);
    float*          O2  = (float*)        (ws + 33816576);
    unsigned short* xb  = (unsigned short*)(ws + 33816576);
    unsigned short* w1b = (unsigned short*)(ws + 33816576 + 8388608);
    char* tail = ws + 33816576 + 34078720;
    float* logits = (float*)(tail);
    int*   list   = (int*)(tail + 131072);
    int*   pairEP = (int*)(tail + 262144);
    float* pairW  = (float*)(tail + 294912);
    int*   counts = (int*)(tail + 327680);

    hipMemsetAsync(counts, 0, 64, stream);

    cvt3_kernel<<<(NGRP_X + 2 * NGRP_W) / 256, 256, 0, stream>>>(x, w1, w2, xb, w1b, w2b);
    logits_kernel<<<NTOK / 4, 256, 0, stream>>>(x, rw, logits);
    assign_kernel<<<NTOK / 256, 256, 0, stream>>>(logits, bias, counts, list, pairEP, pairW);
    gemm1_kernel<<<dim3(16, 256), 256, 0, stream>>>(xb, w1b, counts, list, Hb);
    gemm2_kernel<<<dim3(16, 256), 256, 0, stream>>>(Hb, w2b, counts, O2);
    combine_kernel<<<NTOK, 256, 0, stream>>>(O2, counts, pairEP, pairW, out);
}

// Round 9
// 218.239 us; speedup vs baseline: 1.1035x; 1.0030x over previous
//
#include <hip/hip_runtime.h>
#include <hip/hip_bf16.h>

#define D_DIM 1024
#define F_DIM 1024
#define NTOK  4096
#define NEXP  8
#define CAP   4096
#define NGRP_X (NTOK * D_DIM / 8)
#define NGRP_W (NEXP * F_DIM * D_DIM / 8)

typedef __attribute__((ext_vector_type(8))) short bf16x8;
typedef __attribute__((ext_vector_type(4))) float f32x4;
typedef __attribute__((ext_vector_type(8))) unsigned short u16x8;

__device__ __forceinline__ unsigned short f2bf(float f) {
    unsigned int u = __float_as_uint(f);
    u = u + 0x7fffu + ((u >> 16) & 1u);
    return (unsigned short)(u >> 16);
}

__device__ __forceinline__ void async_copy16(void* lds, const void* gsrc) {
    __builtin_amdgcn_global_load_lds(
        (const __attribute__((address_space(1))) unsigned int*)gsrc,
        (__attribute__((address_space(3))) unsigned int*)lds, 16, 0, 0);
}

// ---------------- fused f32 -> bf16 conversion for x, w1, w2 (1 launch) ----------------
__global__ __launch_bounds__(256) void cvt3_kernel(
    const float* __restrict__ x, const float* __restrict__ w1, const float* __restrict__ w2,
    unsigned short* __restrict__ xb, unsigned short* __restrict__ w1b,
    unsigned short* __restrict__ w2b)
{
    long g = (long)blockIdx.x * 256 + threadIdx.x;   // 8-elem group id
    const float* src; unsigned short* dst; long o;
    if (g < NGRP_X)            { src = x;  dst = xb;  o = g; }
    else if (g < NGRP_X + NGRP_W) { src = w1; dst = w1b; o = g - NGRP_X; }
    else                       { src = w2; dst = w2b; o = g - NGRP_X - NGRP_W; }
    size_t i = (size_t)o * 8;
    const float4* p = (const float4*)(src + i);
    float4 a = p[0], b = p[1];
    u16x8 r;
    r[0] = f2bf(a.x); r[1] = f2bf(a.y); r[2] = f2bf(a.z); r[3] = f2bf(a.w);
    r[4] = f2bf(b.x); r[5] = f2bf(b.y); r[6] = f2bf(b.z); r[7] = f2bf(b.w);
    *(u16x8*)(dst + i) = r;
}

// ---------------- router logits: one wave per token, f64 accumulation ----------------
__global__ __launch_bounds__(256) void logits_kernel(
    const float* __restrict__ x, const float* __restrict__ rw,
    float* __restrict__ logits)
{
    const int wave = threadIdx.x >> 6, lane = threadIdx.x & 63;
    const int t = blockIdx.x * 4 + wave;
    double s[NEXP];
    #pragma unroll
    for (int e = 0; e < NEXP; ++e) s[e] = 0.0;
    const float* xp = x + (size_t)t * D_DIM;
    for (int kk = 0; kk < D_DIM; kk += 64) {
        float xv = xp[kk + lane];
        #pragma unroll
        for (int e = 0; e < NEXP; ++e)
            s[e] += (double)xv * (double)rw[e * D_DIM + kk + lane];
    }
    #pragma unroll
    for (int e = 0; e < NEXP; ++e) {
        double v = s[e];
        for (int off = 32; off; off >>= 1) v += __shfl_xor(v, off, 64);
        s[e] = v;
    }
    if (lane == 0) {
        #pragma unroll
        for (int e = 0; e < NEXP; ++e) logits[(size_t)t * NEXP + e] = (float)s[e];
    }
}

// ---------------- assign: top-2 + softmax + expert lists + per-token pair table ----------------
__global__ __launch_bounds__(256) void assign_kernel(
    const float* __restrict__ logits, const float* __restrict__ bias,
    int* counts, int* list, int* pairEP, float* pairW)
{
    __shared__ int lcnt[NEXP];
    __shared__ int lbase[NEXP];
    const int tid = threadIdx.x;
    const int t = blockIdx.x * 256 + tid;
    if (tid < NEXP) lcnt[tid] = 0;
    __syncthreads();

    float lg[NEXP], b2[NEXP];
    #pragma unroll
    for (int e = 0; e < NEXP; ++e) {
        lg[e] = logits[(size_t)t * NEXP + e];
        b2[e] = lg[e] + bias[e];
    }
    int i0 = 0; float b0v = b2[0], l0v = lg[0];
    #pragma unroll
    for (int e = 1; e < NEXP; ++e)
        if (b2[e] > b0v) { b0v = b2[e]; l0v = lg[e]; i0 = e; }
    int i1 = -1; float b1v = 0.f, l1v = 0.f;
    #pragma unroll
    for (int e = 0; e < NEXP; ++e) {
        if (e == i0) continue;
        bool take = (i1 < 0) || (b2[e] > b1v);
        if (take) { i1 = e; b1v = b2[e]; l1v = lg[e]; }
    }
    float m = fmaxf(l0v, l1v);
    float e0 = expf(l0v - m), e1 = expf(l1v - m);
    float inv = 1.0f / (e0 + e1);

    int lp0 = atomicAdd(&lcnt[i0], 1);
    int lp1 = atomicAdd(&lcnt[i1], 1);
    __syncthreads();
    if (tid < NEXP) lbase[tid] = atomicAdd(&counts[tid], lcnt[tid]);
    __syncthreads();

    int p0 = lbase[i0] + lp0;
    int p1 = lbase[i1] + lp1;
    list[i0 * CAP + p0] = t;
    list[i1 * CAP + p1] = t;
    pairEP[2 * t]     = (p0 << 3) | i0;   // position-in-expert + expert id
    pairEP[2 * t + 1] = (p1 << 3) | i1;
    pairW[2 * t]      = e0 * inv;
    pairW[2 * t + 1]  = e1 * inv;
}

// ======== GEMM machinery (EXACT r6/r8 structure, proven 0-conflict): ========
// ======== BM=128, BN=64, BK=64, single-buffer, stage->sync->compute->sync, ========
// ======== XOR slot swizzle phys = slot ^ (row&7) ========
// NEW (r9): expert<->XCD affinity. block b = slot*8 + e; HW round-robin
// (b%8 -> XCD) pins all of expert e's blocks to XCD e, so W_e (2MB) stays
// L2-resident and each row-panel's 16 col-blocks share one XCD's L2.
#define STAGE(AB, BB, k0)                                                   \
    do {                                                                    \
        _Pragma("unroll")                                                   \
        for (int i = 0; i < 4; ++i)                                         \
            async_copy16(&AB[(wave * 4 + i) * 512], ap[i] + (k0));          \
        _Pragma("unroll")                                                   \
        for (int i = 0; i < 2; ++i)                                         \
            async_copy16(&BB[(wave * 2 + i) * 512], bp_[i] + (k0));         \
    } while (0)

#define COMPUTE(AB, BB)                                                     \
    do {                                                                    \
        _Pragma("unroll")                                                   \
        for (int kk = 0; kk < 2; ++kk) {                                    \
            bf16x8 af[4], bfv[2];                                           \
            const int phys = (((kk * 4) + (lane >> 4)) ^ (lane & 7)) * 8;   \
            _Pragma("unroll")                                               \
            for (int m = 0; m < 4; ++m)                                     \
                af[m] = *(const bf16x8*)&AB[(wr * 64 + m * 16 + (lane & 15)) * 64 + phys]; \
            _Pragma("unroll")                                               \
            for (int n = 0; n < 2; ++n)                                     \
                bfv[n] = *(const bf16x8*)&BB[(wc * 32 + n * 16 + (lane & 15)) * 64 + phys]; \
            _Pragma("unroll")                                               \
            for (int m = 0; m < 4; ++m)                                     \
                _Pragma("unroll")                                           \
                for (int n = 0; n < 2; ++n)                                 \
                    acc[m][n] = __builtin_amdgcn_mfma_f32_16x16x32_bf16(af[m], bfv[n], acc[m][n], 0, 0, 0); \
        }                                                                   \
    } while (0)

// ---------------- grouped GEMM1: H = gelu(Xg @ W1_e^T), bf16 out ----------------
__global__ __launch_bounds__(256) void gemm1_kernel(
    const unsigned short* __restrict__ xb,
    const unsigned short* __restrict__ w1b,
    const int* __restrict__ counts,
    const int* __restrict__ list,
    unsigned short* __restrict__ H)
{
    const int bid = blockIdx.x;
    const int e  = bid & 7;          // XCD affinity: b%8 -> XCD
    const int s  = bid >> 3;         // 512 slots: rb*16 + nx
    const int rb = s >> 4;
    const int ne = counts[e];
    if (rb * 128 >= ne) return;
    const int row0 = rb * 128;
    const int n0 = (s & 15) * 64;
    int hbase = 0;
    #pragma unroll
    for (int ee = 0; ee < NEXP; ++ee) if (ee < e) hbase += counts[ee];

    __shared__ __align__(16) unsigned short As[128 * 64];
    __shared__ __align__(16) unsigned short Bs[64 * 64];
    __shared__ int toks[128];

    const int tid = threadIdx.x;
    if (tid < 128) {
        int i = row0 + tid;
        if (i >= ne) i = ne - 1;
        toks[tid] = list[e * CAP + i];
    }
    __syncthreads();

    const int wave = tid >> 6, lane = tid & 63;
    const int wr = wave >> 1, wc = wave & 1;

    const int lr  = lane >> 3;
    const int swz = ((lane & 7) ^ lr) * 8;
    const unsigned short* ap[4];
    const unsigned short* bp_[2];
    const unsigned short* wbase = w1b + (size_t)e * F_DIM * D_DIM;
    #pragma unroll
    for (int i = 0; i < 4; ++i)
        ap[i] = xb + (size_t)toks[wave * 32 + i * 8 + lr] * D_DIM + swz;
    #pragma unroll
    for (int i = 0; i < 2; ++i)
        bp_[i] = wbase + (size_t)(n0 + wave * 16 + i * 8 + lr) * D_DIM + swz;

    f32x4 acc[4][2];
    #pragma unroll
    for (int m = 0; m < 4; ++m)
        #pragma unroll
        for (int n = 0; n < 2; ++n) acc[m][n] = (f32x4){0.f, 0.f, 0.f, 0.f};

    for (int k0 = 0; k0 < D_DIM; k0 += 64) {
        STAGE(As, Bs, k0);
        __syncthreads();
        COMPUTE(As, Bs);
        __syncthreads();
    }

    #pragma unroll
    for (int m = 0; m < 4; ++m) {
        #pragma unroll
        for (int j = 0; j < 4; ++j) {
            int ri = wr * 64 + m * 16 + (lane >> 4) * 4 + j;
            int i = row0 + ri;
            if (i < ne) {
                unsigned short* hp = H + (size_t)(hbase + i) * F_DIM + n0 + wc * 32;
                #pragma unroll
                for (int n = 0; n < 2; ++n) {
                    float v = acc[m][n][j];
                    float g = 0.5f * v * (1.0f + erff(v * 0.70710678118654752f));
                    hp[n * 16 + (lane & 15)] = f2bf(g);
                }
            }
        }
    }
}

// ---------------- grouped GEMM2: O2 = H @ W2_e^T (plain f32 stores, NO atomics) ----------------
__global__ __launch_bounds__(256) void gemm2_kernel(
    const unsigned short* __restrict__ H,
    const unsigned short* __restrict__ w2b,
    const int* __restrict__ counts,
    float* __restrict__ O2)
{
    const int bid = blockIdx.x;
    const int e  = bid & 7;          // XCD affinity: b%8 -> XCD
    const int s  = bid >> 3;
    const int rb = s >> 4;
    const int ne = counts[e];
    if (rb * 128 >= ne) return;
    const int row0 = rb * 128;
    const int n0 = (s & 15) * 64;
    int hbase = 0;
    #pragma unroll
    for (int ee = 0; ee < NEXP; ++ee) if (ee < e) hbase += counts[ee];

    __shared__ __align__(16) unsigned short As[128 * 64];
    __shared__ __align__(16) unsigned short Bs[64 * 64];

    const int tid = threadIdx.x;
    const int wave = tid >> 6, lane = tid & 63;
    const int wr = wave >> 1, wc = wave & 1;

    const int lr  = lane >> 3;
    const int swz = ((lane & 7) ^ lr) * 8;
    const unsigned short* ap[4];
    const unsigned short* bp_[2];
    const unsigned short* wbase = w2b + (size_t)e * D_DIM * F_DIM;
    #pragma unroll
    for (int i = 0; i < 4; ++i)
        ap[i] = H + (size_t)(hbase + row0 + wave * 32 + i * 8 + lr) * F_DIM + swz;
    #pragma unroll
    for (int i = 0; i < 2; ++i)
        bp_[i] = wbase + (size_t)(n0 + wave * 16 + i * 8 + lr) * F_DIM + swz;

    f32x4 acc[4][2];
    #pragma unroll
    for (int m = 0; m < 4; ++m)
        #pragma unroll
        for (int n = 0; n < 2; ++n) acc[m][n] = (f32x4){0.f, 0.f, 0.f, 0.f};

    for (int k0 = 0; k0 < F_DIM; k0 += 64) {
        STAGE(As, Bs, k0);
        __syncthreads();
        COMPUTE(As, Bs);
        __syncthreads();
    }

    #pragma unroll
    for (int m = 0; m < 4; ++m) {
        #pragma unroll
        for (int j = 0; j < 4; ++j) {
            int ri = wr * 64 + m * 16 + (lane >> 4) * 4 + j;
            int i = row0 + ri;
            if (i < ne) {
                float* op = O2 + (size_t)(hbase + i) * D_DIM + n0 + wc * 32;
                #pragma unroll
                for (int n = 0; n < 2; ++n)
                    op[n * 16 + (lane & 15)] = acc[m][n][j];
            }
        }
    }
}

// ---------------- combine: out[t] = w0*O2[row0] + w1*O2[row1] ----------------
__global__ __launch_bounds__(256) void combine_kernel(
    const float* __restrict__ O2, const int* __restrict__ counts,
    const int* __restrict__ pairEP, const float* __restrict__ pairW,
    float* __restrict__ out)
{
    const int t = blockIdx.x;
    const int tid = threadIdx.x;
    int offs[NEXP];
    int a = 0;
    #pragma unroll
    for (int e = 0; e < NEXP; ++e) { offs[e] = a; a += counts[e]; }
    int ep0 = pairEP[2 * t], ep1 = pairEP[2 * t + 1];
    float w0 = pairW[2 * t], w1 = pairW[2 * t + 1];
    int e0 = ep0 & 7, e1 = ep1 & 7, o0 = 0, o1 = 0;
    #pragma unroll
    for (int e = 0; e < NEXP; ++e) {
        if (e == e0) o0 = offs[e];
        if (e == e1) o1 = offs[e];
    }
    size_t r0 = (size_t)(o0 + (ep0 >> 3)) * D_DIM;
    size_t r1 = (size_t)(o1 + (ep1 >> 3)) * D_DIM;
    float4 va = *(const float4*)(O2 + r0 + tid * 4);
    float4 vb = *(const float4*)(O2 + r1 + tid * 4);
    float4 r;
    r.x = w0 * va.x + w1 * vb.x;
    r.y = w0 * va.y + w1 * vb.y;
    r.z = w0 * va.z + w1 * vb.z;
    r.w = w0 * va.w + w1 * vb.w;
    *(float4*)(out + (size_t)t * D_DIM + tid * 4) = r;
}

extern "C" void kernel_launch(void* const* d_in, const int* in_sizes, int n_in,
                              void* d_out, int out_size, void* d_ws, size_t ws_size,
                              hipStream_t stream)
{
    const float* x    = (const float*)d_in[0];
    const float* bias = (const float*)d_in[1];
    const float* rw   = (const float*)d_in[2];
    const float* w1   = (const float*)d_in[3];
    const float* w2   = (const float*)d_in[4];
    float* out = (float*)d_out;

    char* ws = (char*)d_ws;
    // Layout (bytes, 256-aligned). O2 aliases xb+w1b (dead once gemm2 runs):
    //   [0,16M)      w2b
    //   [16M,33.3M)  Hb   (8320 rows x 1024 bf16)
    //   [33.3M,67.4M) O2  (8320 rows x 1024 f32); xb at O2+0 (8MB), w1b at O2+8MB (16MB)
    //   tail: logits, list, pairEP, pairW, counts
    unsigned short* w2b = (unsigned short*)(ws);
    unsigned short* Hb  = (unsigned short*)(ws + 16777216);
    float*          O2  = (float*)        (ws + 33816576);
    unsigned short* xb  = (unsigned short*)(ws + 33816576);
    unsigned short* w1b = (unsigned short*)(ws + 33816576 + 8388608);
    char* tail = ws + 33816576 + 34078720;
    float* logits = (float*)(tail);
    int*   list   = (int*)(tail + 131072);
    int*   pairEP = (int*)(tail + 262144);
    float* pairW  = (float*)(tail + 294912);
    int*   counts = (int*)(tail + 327680);

    hipMemsetAsync(counts, 0, 64, stream);

    cvt3_kernel<<<(NGRP_X + 2 * NGRP_W) / 256, 256, 0, stream>>>(x, w1, w2, xb, w1b, w2b);
    logits_kernel<<<NTOK / 4, 256, 0, stream>>>(x, rw, logits);
    assign_kernel<<<NTOK / 256, 256, 0, stream>>>(logits, bias, counts, list, pairEP, pairW);
    gemm1_kernel<<<4096, 256, 0, stream>>>(xb, w1b, counts, list, Hb);
    gemm2_kernel<<<4096, 256, 0, stream>>>(Hb, w2b, counts, O2);
    combine_kernel<<<NTOK, 256, 0, stream>>>(O2, counts, pairEP, pairW, out);
}